// Round 12
// baseline (379.131 us; speedup 1.0000x reference)
//
#include <hip/hip_runtime.h>
#include <hip/hip_bf16.h>

#define DIMK 3
#define NPTS 30
#define KK   181
#define PP   24360
#define DEMB 190
#define VLD  192   // padded vec row stride (floats)
#define SNP  24576 // padded sort-row length = 16*1536

// ---------------------------------------------------------------------------
// Kernel 1: per-permutation inner embed -> vec (PP x VLD)   [frozen, round 11]
// ---------------------------------------------------------------------------
__global__ __launch_bounds__(256, 5) void k_inner(
    const float* __restrict__ M,      // 3 x 30
    const float* __restrict__ Ws_in,  // 181 x 3
    const float* __restrict__ Wd_in,  // 181 x 27
    float* __restrict__ vec)          // PP x VLD
{
    __shared__ float Gs[NPTS * 32];     // rows padded to 32 (3.84 KB)
    __shared__ float WsS[192 * 3];      // zero-padded (2.3 KB)
    __shared__ float WdS[192 * 28];     // stride 28, zero-padded (21.5 KB)

    const int tid = threadIdx.x;

    for (int i = tid; i < 192 * 3; i += 256) WsS[i] = (i < KK * 3) ? Ws_in[i] : 0.f;
    for (int i = tid; i < 192 * 28; i += 256) {
        int k = i / 28, m = i - k * 28;
        WdS[i] = (k < KK && m < 27) ? Wd_in[k * 27 + m] : 0.f;
    }
    for (int e = tid; e < NPTS * 32; e += 256) {
        int a = e >> 5, b = e & 31;
        Gs[e] = (b < NPTS)
            ? (M[a] * M[b] + M[NPTS + a] * M[NPTS + b] + M[2 * NPTS + a] * M[2 * NPTS + b])
            : 0.f;
    }
    __syncthreads();

    const int wave = tid >> 6;
    const int lane = tid & 63;
    const int wid = blockIdx.x * 4 + wave;    // 0..5119
    const int chunk = wid % 3;
    const int pstream = wid / 3;
    const int nstream = (chunk == 2) ? 1706 : 1707;
    const int k = chunk * 64 + lane;          // 0..191

    const float INF = __builtin_inff();
    const bool kvalid = (k < KK);
    const float w0 = WsS[k * 3 + 0];
    const float w1 = WsS[k * 3 + 1];
    const float w2 = WsS[k * 3 + 2];
    const float* wd = WdS + k * 28;

    for (int p = pstream; p < PP; p += nstream) {
        int i0 = p / 812;            // 812 = 29*28
        int r  = p - i0 * 812;
        int i1 = r / 28;
        int i2 = r - i1 * 28;
        int c0 = i0;
        int c1 = i1 + (i1 >= c0 ? 1 : 0);
        int lo = min(c0, c1), hi = max(c0, c1);
        int c2 = i2;
        if (c2 >= lo) c2++;
        if (c2 >= hi) c2++;

        float* vrow = vec + (long)p * VLD;

        if (chunk == 0 && lane < 9) {
            int i = lane / 3, j = lane % 3;
            int ci = (i == 0) ? c0 : ((i == 1) ? c1 : c2);
            int cj = (j == 0) ? c0 : ((j == 1) ? c1 : c2);
            vrow[lane] = Gs[(ci << 5) + cj];
        }

        const float* g0 = Gs + (c0 << 5);
        const float* g1 = Gs + (c1 << 5);
        const float* g2 = Gs + (c2 << 5);
        const unsigned xmask = (1u << c0) | (1u << c1) | (1u << c2);

        float v[32];
#pragma unroll
        for (int q = 0; q < 8; ++q) {
            float4 x0 = *(const float4*)&g0[q * 4];
            float4 x1 = *(const float4*)&g1[q * 4];
            float4 x2 = *(const float4*)&g2[q * 4];
            int j0 = q * 4;
            if (j0 + 0 < NPTS) { float val = w0 * x0.x + w1 * x1.x + w2 * x2.x;
                v[j0 + 0] = ((xmask >> (j0 + 0)) & 1u) ? INF : val; }
            if (j0 + 1 < NPTS) { float val = w0 * x0.y + w1 * x1.y + w2 * x2.y;
                v[j0 + 1] = ((xmask >> (j0 + 1)) & 1u) ? INF : val; }
            if (j0 + 2 < NPTS) { float val = w0 * x0.z + w1 * x1.z + w2 * x2.z;
                v[j0 + 2] = ((xmask >> (j0 + 2)) & 1u) ? INF : val; }
            if (j0 + 3 < NPTS) { float val = w0 * x0.w + w1 * x1.w + w2 * x2.w;
                v[j0 + 3] = ((xmask >> (j0 + 3)) & 1u) ? INF : val; }
        }
        v[30] = INF;
        v[31] = INF;

        // Batcher odd-even mergesort, n=32, ascending (191 compare-exchanges)
#pragma unroll
        for (int pw = 1; pw < 32; pw <<= 1) {
#pragma unroll
            for (int kk = pw; kk >= 1; kk >>= 1) {
#pragma unroll
                for (int j = kk % pw; j + kk < 32; j += 2 * kk) {
#pragma unroll
                    for (int i = 0; i < kk; ++i) {
                        int a = i + j, b = i + j + kk;
                        if (a / (pw * 2) == b / (pw * 2)) {
                            float x = v[a], y = v[b];
                            v[a] = fminf(x, y);
                            v[b] = fmaxf(x, y);
                        }
                    }
                }
            }
        }

        if (kvalid) {
            v[27] = 0.f;
            float emb = 0.f;
#pragma unroll
            for (int q = 0; q < 7; ++q) {
                float4 w4 = *(const float4*)&wd[q * 4];
                emb += w4.x * v[q * 4] + w4.y * v[q * 4 + 1]
                     + w4.z * v[q * 4 + 2] + w4.w * v[q * 4 + 3];
            }
            vrow[9 + k] = emb;
        } else if (k < 183) {
            vrow[9 + k] = 0.f;
        }
    }
}

// ---------------------------------------------------------------------------
// Kernel 2: sm2T[k][p] = dot(vec[p][0:190], Ws_out[k][0:190])
// Round-12: GDC=24 double-buffered chunks -> LDS 38.4 KB -> genuine 4 blocks
// /CU (round-11's (256,4) was unreachable at 76.6 KB -> 2 blocks/CU).
// Pow2-friendly staging indices; 1 barrier per chunk x 8 chunks.
// ---------------------------------------------------------------------------
#define GBP 128
#define GBK 64
#define GDC 24
#define LDA 132   // As row stride (128 + 4, keeps 16B alignment)
#define LDB 68    // Bs row stride (64 + 4)

__global__ __launch_bounds__(256, 4) void k_gemm(
    const float* __restrict__ vec,    // PP x VLD
    const float* __restrict__ Wout,   // 181 x 190
    float* __restrict__ sm2T)         // 181 x PP
{
    __shared__ float As[2][GDC * LDA];   // 2 x 12.7 KB, [d][pl]
    __shared__ float Bs[2][GDC * LDB];   // 2 x 6.5 KB,  [d][kl]

    const int tid = threadIdx.x;
    const int pTile = blockIdx.x * GBP;
    const int kTile = blockIdx.y * GBK;
    const int tx = tid & 15;   // p dir, 8 p's each
    const int ty = tid >> 4;   // k dir, 4 k's each

    // staging coords (all pow2 shifts/masks)
    const int apl = tid >> 1;         // A row 0..127
    const int ah  = tid & 1;          // half: 3 float4 each
    const int bkl = tid >> 2;         // B row 0..63
    const int bq  = tid & 3;          // quarter: 6 scalars each

    float acc[8][4];
#pragma unroll
    for (int i = 0; i < 8; ++i)
#pragma unroll
        for (int j = 0; j < 4; ++j) acc[i][j] = 0.f;

    float4 ta[3];
    float  tb[6];

#define LOADCH(DB) do {                                                        \
    int pg = pTile + apl;                                                      \
    _Pragma("unroll")                                                          \
    for (int it = 0; it < 3; ++it) {                                           \
        int q = ah * 3 + it;                                                   \
        ta[it] = make_float4(0.f, 0.f, 0.f, 0.f);                              \
        if (pg < PP) ta[it] = *(const float4*)&vec[(long)pg * VLD + (DB) + q * 4]; \
    }                                                                          \
    int kg = kTile + bkl;                                                      \
    _Pragma("unroll")                                                          \
    for (int it = 0; it < 6; ++it) {                                           \
        int dg = (DB) + bq * 6 + it;                                           \
        tb[it] = (kg < KK && dg < DEMB) ? Wout[kg * DEMB + dg] : 0.f;          \
    }                                                                          \
} while (0)

#define STORECH(B) do {                                                        \
    _Pragma("unroll")                                                          \
    for (int it = 0; it < 3; ++it) {                                           \
        int d0 = (ah * 3 + it) * 4;                                            \
        As[B][(d0 + 0) * LDA + apl] = ta[it].x;                                \
        As[B][(d0 + 1) * LDA + apl] = ta[it].y;                                \
        As[B][(d0 + 2) * LDA + apl] = ta[it].z;                                \
        As[B][(d0 + 3) * LDA + apl] = ta[it].w;                                \
    }                                                                          \
    _Pragma("unroll")                                                          \
    for (int it = 0; it < 6; ++it) {                                           \
        int d = bq * 6 + it;                                                   \
        Bs[B][d * LDB + bkl] = tb[it];                                         \
    }                                                                          \
} while (0)

    LOADCH(0);
    STORECH(0);

    for (int ch = 0; ch < 8; ++ch) {
        const int cur = ch & 1;
        __syncthreads();
        if (ch < 7) LOADCH((ch + 1) * GDC);

        for (int d = 0; d < GDC; ++d) {
            float4 a0 = *(const float4*)&As[cur][d * LDA + tx * 8];
            float4 a1 = *(const float4*)&As[cur][d * LDA + tx * 8 + 4];
            float4 b0 = *(const float4*)&Bs[cur][d * LDB + ty * 4];
            float a[8] = {a0.x, a0.y, a0.z, a0.w, a1.x, a1.y, a1.z, a1.w};
            float b[4] = {b0.x, b0.y, b0.z, b0.w};
#pragma unroll
            for (int i = 0; i < 8; ++i)
#pragma unroll
                for (int j = 0; j < 4; ++j) acc[i][j] += a[i] * b[j];
        }

        if (ch < 7) STORECH(cur ^ 1);
    }
#undef LOADCH
#undef STORECH

#pragma unroll
    for (int j = 0; j < 4; ++j) {
        int kg = kTile + ty * 4 + j;
        if (kg < KK) {
            int pg0 = pTile + tx * 8;
            if (pg0 < PP) {
                float4 s0 = {acc[0][j], acc[1][j], acc[2][j], acc[3][j]};
                float4 s1 = {acc[4][j], acc[5][j], acc[6][j], acc[7][j]};
                *(float4*)&sm2T[(long)kg * PP + pg0]     = s0;
                *(float4*)&sm2T[(long)kg * PP + pg0 + 4] = s1;
            }
        }
    }
}

// ---------------------------------------------------------------------------
// Kernel 3: per-k LSD radix sort on the HIGH 24 BITS only (3 x 8-bit passes;
// low-8-bit ties are interchangeable within the 2% output tolerance:
// error <= 2^-15 * sum|Wd*v| ~ O(100) << 3358). Rows padded to SNP=24576
// with 0xFFFFFFFF keys (strictly larger than any finite encoded value ->
// pads provably land at dest in [PP,SNP), skipped by the dest<PP dot guard),
// so passes 1-2 run all-lanes-valid with matchany8. Fused next-pass
// histograms + fused final dot. Traversals 5 -> 4, ballot passes 4 -> 3.
// ---------------------------------------------------------------------------
#define WAVES  16
#define WCHUNK 1536             // 64 lanes * 24 iters; 16*1536 = SNP exactly

__device__ __forceinline__ unsigned long long matchany9(unsigned d) {
    unsigned long long m = ~0ull;
#pragma unroll
    for (int b = 0; b < 9; ++b) {
        unsigned bit = (d >> b) & 1u;
        unsigned long long bal = __ballot(bit);
        m &= bit ? bal : ~bal;
    }
    return m;
}

__device__ __forceinline__ unsigned long long matchany8(unsigned d) {
    unsigned long long m = ~0ull;
#pragma unroll
    for (int b = 0; b < 8; ++b) {
        unsigned bit = (d >> b) & 1u;
        unsigned long long bal = __ballot(bit);
        m &= bit ? bal : ~bal;
    }
    return m;
}

// counts in cntC -> stable scatter offsets in cntC; cntZ (if non-null) zeroed.
__device__ __forceinline__ void scan_hist(unsigned* cntC, unsigned* cntZ,
                                          unsigned* tot, int tid) {
    if (tid < 256) {            // exclusive prefix across waves, per digit
        unsigned run = 0;
        for (int w = 0; w < WAVES; ++w) {
            unsigned t = cntC[w * 256 + tid];
            cntC[w * 256 + tid] = run;
            run += t;
        }
        tot[tid] = run;
    }
    __syncthreads();
    if (tid < 64) {             // inclusive scan of tot[256], 4 bins/lane
        unsigned t0 = tot[tid * 4], t1 = tot[tid * 4 + 1];
        unsigned t2 = tot[tid * 4 + 2], t3 = tot[tid * 4 + 3];
        unsigned s = t0 + t1 + t2 + t3;
        unsigned sc = s;
#pragma unroll
        for (int off = 1; off < 64; off <<= 1) {
            unsigned o = (unsigned)__shfl_up((int)sc, off, 64);
            if (tid >= off) sc += o;
        }
        unsigned ex = sc - s;
        tot[tid * 4]     = ex + t0;
        tot[tid * 4 + 1] = ex + t0 + t1;
        tot[tid * 4 + 2] = ex + t0 + t1 + t2;
        tot[tid * 4 + 3] = ex + s;
    } else if (cntZ) {
        for (int i = tid - 64; i < WAVES * 256; i += 1024 - 64) cntZ[i] = 0;
    }
    __syncthreads();
    for (int i = tid; i < WAVES * 256; i += 1024) {
        int d = i & 255;
        unsigned db = (d == 0) ? 0u : tot[d - 1];
        cntC[i] += db;
    }
    __syncthreads();
}

__global__ __launch_bounds__(1024) void k_sort(
    float* sm2T,              // 181 x PP (row k read as pass-0 source)
    unsigned* bufA,           // 181 x SNP scratch, padded stride (overlays dead vec)
    const float* __restrict__ WdOut,  // 181 x PP
    float* __restrict__ out)          // 181
{
    __shared__ unsigned keysL[SNP];         // 96.3 KiB
    __shared__ unsigned cntA[WAVES * 256];  // 16 KiB
    __shared__ unsigned cntB[WAVES * 256];  // 16 KiB
    __shared__ unsigned tot[256];
    __shared__ float red[WAVES];

    const int tid  = threadIdx.x;
    const int wave = tid >> 6;
    const int lane = tid & 63;
    const int k    = blockIdx.x;

    const unsigned* rowU = (const unsigned*)sm2T + (long)k * PP;
    unsigned* bA         = bufA + (long)k * SNP;
    const float* wrow    = WdOut + (long)k * PP;

    const int base_idx = wave * WCHUNK + lane;
    const int wbase = wave * 256;
    const unsigned long long lt_mask = (1ull << lane) - 1ull;

    // init: zero cntA; pad keysL tail with max keys
    for (int i = tid; i < WAVES * 256; i += 1024) cntA[i] = 0;
    for (int i = PP + tid; i < SNP; i += 1024) keysL[i] = 0xFFFFFFFFu;
    __syncthreads();

    // ---- count0: digit bits 8-15 over real elements ----
    for (int j = 0; j < 24; ++j) {
        int idx = base_idx + j * 64;
        if (idx < PP) {
            unsigned u = rowU[idx];
            u = (u & 0x80000000u) ? ~u : (u | 0x80000000u);
            atomicAdd(&cntA[wbase + ((u >> 8) & 255u)], 1u);
        }
    }
    __syncthreads();
    scan_hist(cntA, cntB, tot, tid);   // also zeroes cntB

    // ---- scatter0: G -> LDS on bits 8-15 (matchany9, tail-guarded),
    //      fused count1 (bits 16-23) binned by destination wave ----
    for (int j = 0; j < 24; ++j) {
        int idx = base_idx + j * 64;
        bool valid = (idx < PP);
        unsigned u = 0u;
        if (valid) {
            u = rowU[idx];
            u = (u & 0x80000000u) ? ~u : (u | 0x80000000u);
        }
        unsigned d9 = ((u >> 8) & 255u) | (valid ? 0u : 256u);
        unsigned long long mm = matchany9(d9);
        if (valid) {
            int leader = __ffsll(mm) - 1;
            unsigned myrank = (unsigned)__popcll(mm & lt_mask);
            unsigned old = 0;
            if (lane == leader)
                old = atomicAdd(&cntA[wbase + (d9 & 255u)], (unsigned)__popcll(mm));
            old = (unsigned)__shfl((int)old, leader, 64);
            unsigned dest = old + myrank;
            keysL[dest] = u;
            atomicAdd(&cntB[(dest / WCHUNK) * 256 + ((u >> 16) & 255u)], 1u);
        }
    }
    __syncthreads();
    // pads: 216 keys 0xFFFFFFFF at keysL[PP..SNP) = pass-1 wave 15, digit 255
    if (tid == 0) cntB[15 * 256 + 255] += (SNP - PP);
    __syncthreads();
    scan_hist(cntB, cntA, tot, tid);   // zeroes cntA

    // ---- scatter1: LDS -> G(bA, padded) on bits 16-23 (matchany8, all valid),
    //      fused count2 (bits 24-31) binned by destination wave ----
    for (int j = 0; j < 24; ++j) {
        int idx = base_idx + j * 64;
        unsigned u = keysL[idx];
        unsigned d = (u >> 16) & 255u;
        unsigned long long mm = matchany8(d);
        int leader = __ffsll(mm) - 1;
        unsigned myrank = (unsigned)__popcll(mm & lt_mask);
        unsigned old = 0;
        if (lane == leader)
            old = atomicAdd(&cntB[wbase + d], (unsigned)__popcll(mm));
        old = (unsigned)__shfl((int)old, leader, 64);
        unsigned dest = old + myrank;
        bA[dest] = u;
        atomicAdd(&cntA[(dest / WCHUNK) * 256 + ((u >> 24) & 255u)], 1u);
    }
    __syncthreads();
    scan_hist(cntA, (unsigned*)0, tot, tid);

    // ---- scatter2: G -> fused dot on bits 24-31 (matchany8, all valid) ----
    float local = 0.f;
    for (int j = 0; j < 24; ++j) {
        int idx = base_idx + j * 64;
        unsigned u = bA[idx];
        unsigned d = (u >> 24) & 255u;
        unsigned long long mm = matchany8(d);
        int leader = __ffsll(mm) - 1;
        unsigned myrank = (unsigned)__popcll(mm & lt_mask);
        unsigned old = 0;
        if (lane == leader)
            old = atomicAdd(&cntA[wbase + d], (unsigned)__popcll(mm));
        old = (unsigned)__shfl((int)old, leader, 64);
        unsigned dest = old + myrank;
        if (dest < PP) {
            unsigned raw = (u & 0x80000000u) ? (u & 0x7FFFFFFFu) : ~u;
            local += wrow[dest] * __uint_as_float(raw);
        }
    }

    // block reduction of local
#pragma unroll
    for (int off = 32; off > 0; off >>= 1)
        local += __shfl_down(local, off, 64);
    if (lane == 0) red[wave] = local;
    __syncthreads();
    if (tid < WAVES) {
        float x = red[tid];
#pragma unroll
        for (int off = 8; off > 0; off >>= 1)
            x += __shfl_down(x, off, 64);
        if (tid == 0) out[k] = x;
    }
}

// ---------------------------------------------------------------------------
extern "C" void kernel_launch(void* const* d_in, const int* in_sizes, int n_in,
                              void* d_out, int out_size, void* d_ws, size_t ws_size,
                              hipStream_t stream) {
    const float* M      = (const float*)d_in[0];
    const float* Ws_in  = (const float*)d_in[1];
    const float* Wd_in  = (const float*)d_in[2];
    const float* Ws_out = (const float*)d_in[3];
    const float* Wd_out = (const float*)d_in[4];
    float* out = (float*)d_out;

    float* vec  = (float*)d_ws;                    // PP*VLD floats = 18.71 MB
    float* sm2T = vec + (size_t)PP * VLD;          // KK*PP floats  = 17.64 MB
    // k_sort scratch overlays vec (dead after k_gemm): KK*SNP u32 = 17.80 MB <= 18.71 MB
    unsigned* bufA = (unsigned*)d_ws;

    k_inner<<<1280, 256, 0, stream>>>(M, Ws_in, Wd_in, vec);

    dim3 g2((PP + GBP - 1) / GBP, (KK + GBK - 1) / GBK);
    k_gemm<<<g2, 256, 0, stream>>>(vec, Ws_out, sm2T);

    k_sort<<<KK, 1024, 0, stream>>>(sm2T, bufA, Wd_out, out);
}

// Round 13
// 279.943 us; speedup vs baseline: 1.3543x; 1.3543x over previous
//
#include <hip/hip_runtime.h>
#include <hip/hip_bf16.h>

#define DIMK 3
#define NPTS 30
#define KK   181
#define PP   24360
#define DEMB 190
#define VLD  192   // padded vec row stride (floats)
#define SNP  24576 // padded sort-row length = 16*1536

// ---------------------------------------------------------------------------
// Kernel 1: per-permutation inner embed -> vec (PP x VLD)   [frozen, round 11]
// ---------------------------------------------------------------------------
__global__ __launch_bounds__(256, 5) void k_inner(
    const float* __restrict__ M,      // 3 x 30
    const float* __restrict__ Ws_in,  // 181 x 3
    const float* __restrict__ Wd_in,  // 181 x 27
    float* __restrict__ vec)          // PP x VLD
{
    __shared__ float Gs[NPTS * 32];     // rows padded to 32 (3.84 KB)
    __shared__ float WsS[192 * 3];      // zero-padded (2.3 KB)
    __shared__ float WdS[192 * 28];     // stride 28, zero-padded (21.5 KB)

    const int tid = threadIdx.x;

    for (int i = tid; i < 192 * 3; i += 256) WsS[i] = (i < KK * 3) ? Ws_in[i] : 0.f;
    for (int i = tid; i < 192 * 28; i += 256) {
        int k = i / 28, m = i - k * 28;
        WdS[i] = (k < KK && m < 27) ? Wd_in[k * 27 + m] : 0.f;
    }
    for (int e = tid; e < NPTS * 32; e += 256) {
        int a = e >> 5, b = e & 31;
        Gs[e] = (b < NPTS)
            ? (M[a] * M[b] + M[NPTS + a] * M[NPTS + b] + M[2 * NPTS + a] * M[2 * NPTS + b])
            : 0.f;
    }
    __syncthreads();

    const int wave = tid >> 6;
    const int lane = tid & 63;
    const int wid = blockIdx.x * 4 + wave;    // 0..5119
    const int chunk = wid % 3;
    const int pstream = wid / 3;
    const int nstream = (chunk == 2) ? 1706 : 1707;
    const int k = chunk * 64 + lane;          // 0..191

    const float INF = __builtin_inff();
    const bool kvalid = (k < KK);
    const float w0 = WsS[k * 3 + 0];
    const float w1 = WsS[k * 3 + 1];
    const float w2 = WsS[k * 3 + 2];
    const float* wd = WdS + k * 28;

    for (int p = pstream; p < PP; p += nstream) {
        int i0 = p / 812;            // 812 = 29*28
        int r  = p - i0 * 812;
        int i1 = r / 28;
        int i2 = r - i1 * 28;
        int c0 = i0;
        int c1 = i1 + (i1 >= c0 ? 1 : 0);
        int lo = min(c0, c1), hi = max(c0, c1);
        int c2 = i2;
        if (c2 >= lo) c2++;
        if (c2 >= hi) c2++;

        float* vrow = vec + (long)p * VLD;

        if (chunk == 0 && lane < 9) {
            int i = lane / 3, j = lane % 3;
            int ci = (i == 0) ? c0 : ((i == 1) ? c1 : c2);
            int cj = (j == 0) ? c0 : ((j == 1) ? c1 : c2);
            vrow[lane] = Gs[(ci << 5) + cj];
        }

        const float* g0 = Gs + (c0 << 5);
        const float* g1 = Gs + (c1 << 5);
        const float* g2 = Gs + (c2 << 5);
        const unsigned xmask = (1u << c0) | (1u << c1) | (1u << c2);

        float v[32];
#pragma unroll
        for (int q = 0; q < 8; ++q) {
            float4 x0 = *(const float4*)&g0[q * 4];
            float4 x1 = *(const float4*)&g1[q * 4];
            float4 x2 = *(const float4*)&g2[q * 4];
            int j0 = q * 4;
            if (j0 + 0 < NPTS) { float val = w0 * x0.x + w1 * x1.x + w2 * x2.x;
                v[j0 + 0] = ((xmask >> (j0 + 0)) & 1u) ? INF : val; }
            if (j0 + 1 < NPTS) { float val = w0 * x0.y + w1 * x1.y + w2 * x2.y;
                v[j0 + 1] = ((xmask >> (j0 + 1)) & 1u) ? INF : val; }
            if (j0 + 2 < NPTS) { float val = w0 * x0.z + w1 * x1.z + w2 * x2.z;
                v[j0 + 2] = ((xmask >> (j0 + 2)) & 1u) ? INF : val; }
            if (j0 + 3 < NPTS) { float val = w0 * x0.w + w1 * x1.w + w2 * x2.w;
                v[j0 + 3] = ((xmask >> (j0 + 3)) & 1u) ? INF : val; }
        }
        v[30] = INF;
        v[31] = INF;

        // Batcher odd-even mergesort, n=32, ascending (191 compare-exchanges)
#pragma unroll
        for (int pw = 1; pw < 32; pw <<= 1) {
#pragma unroll
            for (int kk = pw; kk >= 1; kk >>= 1) {
#pragma unroll
                for (int j = kk % pw; j + kk < 32; j += 2 * kk) {
#pragma unroll
                    for (int i = 0; i < kk; ++i) {
                        int a = i + j, b = i + j + kk;
                        if (a / (pw * 2) == b / (pw * 2)) {
                            float x = v[a], y = v[b];
                            v[a] = fminf(x, y);
                            v[b] = fmaxf(x, y);
                        }
                    }
                }
            }
        }

        if (kvalid) {
            v[27] = 0.f;
            float emb = 0.f;
#pragma unroll
            for (int q = 0; q < 7; ++q) {
                float4 w4 = *(const float4*)&wd[q * 4];
                emb += w4.x * v[q * 4] + w4.y * v[q * 4 + 1]
                     + w4.z * v[q * 4 + 2] + w4.w * v[q * 4 + 3];
            }
            vrow[9 + k] = emb;
        } else if (k < 183) {
            vrow[9 + k] = 0.f;
        }
    }
}

// ---------------------------------------------------------------------------
// Kernel 2: sm2T[k][p] = dot(vec[p][0:190], Ws_out[k][0:190])
// REVERTED to the round-10 measured-good version (GDC=48, single-buffered,
// ~90 us). Round-12's GDC=24 split fragmented row reads into 96-B chunks
// straddling 128-B L2 lines + thrashed inter-chunk reuse -> FETCH 271 MB,
// WRITE 157 MB, 140-180 us. Do not re-fragment the d-dimension.
// ---------------------------------------------------------------------------
#define GBP 128
#define GBK 64
#define GDC 48
#define LDA 132   // As row stride (128 + 4, keeps 16B alignment)
#define LDB 68    // Bs row stride (64 + 4)

__global__ __launch_bounds__(256) void k_gemm(
    const float* __restrict__ vec,    // PP x VLD
    const float* __restrict__ Wout,   // 181 x 190
    float* __restrict__ sm2T)         // 181 x PP
{
    __shared__ float As[GDC * LDA];   // [d][pl]
    __shared__ float Bs[GDC * LDB];   // [d][kl]

    const int tid = threadIdx.x;
    const int pTile = blockIdx.x * GBP;
    const int kTile = blockIdx.y * GBK;
    const int tx = tid & 15;   // p dir, 8 p's each
    const int ty = tid >> 4;   // k dir, 4 k's each

    float acc[8][4];
#pragma unroll
    for (int i = 0; i < 8; ++i)
#pragma unroll
        for (int j = 0; j < 4; ++j) acc[i][j] = 0.f;

    for (int ch = 0; ch < 4; ++ch) {
        const int db = ch * GDC;
        __syncthreads();
        // stage A: 128 rows x 48 d (float4 over d, transposed into LDS)
        for (int e = tid; e < GBP * (GDC / 4); e += 256) {   // 1536
            int q = e % 12, pl = e / 12;
            int pg = pTile + pl;
            float4 v = make_float4(0.f, 0.f, 0.f, 0.f);
            if (pg < PP) v = *(const float4*)&vec[(long)pg * VLD + db + q * 4];
            int d0 = q * 4;
            As[(d0 + 0) * LDA + pl] = v.x;
            As[(d0 + 1) * LDA + pl] = v.y;
            As[(d0 + 2) * LDA + pl] = v.z;
            As[(d0 + 3) * LDA + pl] = v.w;
        }
        // stage B: 64 rows x 48 d (scalar; Wout rows are 190 floats, unaligned)
        for (int e = tid; e < GBK * GDC; e += 256) {         // 3072
            int d = e % GDC, kl = e / GDC;
            int kg = kTile + kl, dg = db + d;
            Bs[d * LDB + kl] = (kg < KK && dg < DEMB) ? Wout[kg * DEMB + dg] : 0.f;
        }
        __syncthreads();

        for (int d = 0; d < GDC; ++d) {
            float4 a0 = *(const float4*)&As[d * LDA + tx * 8];
            float4 a1 = *(const float4*)&As[d * LDA + tx * 8 + 4];
            float4 b0 = *(const float4*)&Bs[d * LDB + ty * 4];
            float a[8] = {a0.x, a0.y, a0.z, a0.w, a1.x, a1.y, a1.z, a1.w};
            float b[4] = {b0.x, b0.y, b0.z, b0.w};
#pragma unroll
            for (int i = 0; i < 8; ++i)
#pragma unroll
                for (int j = 0; j < 4; ++j) acc[i][j] += a[i] * b[j];
        }
    }

#pragma unroll
    for (int j = 0; j < 4; ++j) {
        int kg = kTile + ty * 4 + j;
        if (kg < KK) {
            int pg0 = pTile + tx * 8;
            if (pg0 < PP) {   // PP % 8 == 0: float4 pairs fully valid or fully out
                float4 s0 = {acc[0][j], acc[1][j], acc[2][j], acc[3][j]};
                float4 s1 = {acc[4][j], acc[5][j], acc[6][j], acc[7][j]};
                *(float4*)&sm2T[(long)kg * PP + pg0]     = s0;
                *(float4*)&sm2T[(long)kg * PP + pg0 + 4] = s1;
            }
        }
    }
}

// ---------------------------------------------------------------------------
// Kernel 3: per-k LSD radix sort on the HIGH 24 BITS only (3 x 8-bit passes)
// [round 12]. Rows padded to SNP with 0xFFFFFFFF keys; passes 1-2 all-valid
// matchany8; fused next-pass histograms + fused final dot.
// ---------------------------------------------------------------------------
#define WAVES  16
#define WCHUNK 1536             // 64 lanes * 24 iters; 16*1536 = SNP exactly

__device__ __forceinline__ unsigned long long matchany9(unsigned d) {
    unsigned long long m = ~0ull;
#pragma unroll
    for (int b = 0; b < 9; ++b) {
        unsigned bit = (d >> b) & 1u;
        unsigned long long bal = __ballot(bit);
        m &= bit ? bal : ~bal;
    }
    return m;
}

__device__ __forceinline__ unsigned long long matchany8(unsigned d) {
    unsigned long long m = ~0ull;
#pragma unroll
    for (int b = 0; b < 8; ++b) {
        unsigned bit = (d >> b) & 1u;
        unsigned long long bal = __ballot(bit);
        m &= bit ? bal : ~bal;
    }
    return m;
}

// counts in cntC -> stable scatter offsets in cntC; cntZ (if non-null) zeroed.
__device__ __forceinline__ void scan_hist(unsigned* cntC, unsigned* cntZ,
                                          unsigned* tot, int tid) {
    if (tid < 256) {            // exclusive prefix across waves, per digit
        unsigned run = 0;
        for (int w = 0; w < WAVES; ++w) {
            unsigned t = cntC[w * 256 + tid];
            cntC[w * 256 + tid] = run;
            run += t;
        }
        tot[tid] = run;
    }
    __syncthreads();
    if (tid < 64) {             // inclusive scan of tot[256], 4 bins/lane
        unsigned t0 = tot[tid * 4], t1 = tot[tid * 4 + 1];
        unsigned t2 = tot[tid * 4 + 2], t3 = tot[tid * 4 + 3];
        unsigned s = t0 + t1 + t2 + t3;
        unsigned sc = s;
#pragma unroll
        for (int off = 1; off < 64; off <<= 1) {
            unsigned o = (unsigned)__shfl_up((int)sc, off, 64);
            if (tid >= off) sc += o;
        }
        unsigned ex = sc - s;
        tot[tid * 4]     = ex + t0;
        tot[tid * 4 + 1] = ex + t0 + t1;
        tot[tid * 4 + 2] = ex + t0 + t1 + t2;
        tot[tid * 4 + 3] = ex + s;
    } else if (cntZ) {
        for (int i = tid - 64; i < WAVES * 256; i += 1024 - 64) cntZ[i] = 0;
    }
    __syncthreads();
    for (int i = tid; i < WAVES * 256; i += 1024) {
        int d = i & 255;
        unsigned db = (d == 0) ? 0u : tot[d - 1];
        cntC[i] += db;
    }
    __syncthreads();
}

__global__ __launch_bounds__(1024) void k_sort(
    float* sm2T,              // 181 x PP (row k read as pass-0 source)
    unsigned* bufA,           // 181 x SNP scratch, padded stride (overlays dead vec)
    const float* __restrict__ WdOut,  // 181 x PP
    float* __restrict__ out)          // 181
{
    __shared__ unsigned keysL[SNP];         // 96.3 KiB
    __shared__ unsigned cntA[WAVES * 256];  // 16 KiB
    __shared__ unsigned cntB[WAVES * 256];  // 16 KiB
    __shared__ unsigned tot[256];
    __shared__ float red[WAVES];

    const int tid  = threadIdx.x;
    const int wave = tid >> 6;
    const int lane = tid & 63;
    const int k    = blockIdx.x;

    const unsigned* rowU = (const unsigned*)sm2T + (long)k * PP;
    unsigned* bA         = bufA + (long)k * SNP;
    const float* wrow    = WdOut + (long)k * PP;

    const int base_idx = wave * WCHUNK + lane;
    const int wbase = wave * 256;
    const unsigned long long lt_mask = (1ull << lane) - 1ull;

    // init: zero cntA; pad keysL tail with max keys
    for (int i = tid; i < WAVES * 256; i += 1024) cntA[i] = 0;
    for (int i = PP + tid; i < SNP; i += 1024) keysL[i] = 0xFFFFFFFFu;
    __syncthreads();

    // ---- count0: digit bits 8-15 over real elements ----
    for (int j = 0; j < 24; ++j) {
        int idx = base_idx + j * 64;
        if (idx < PP) {
            unsigned u = rowU[idx];
            u = (u & 0x80000000u) ? ~u : (u | 0x80000000u);
            atomicAdd(&cntA[wbase + ((u >> 8) & 255u)], 1u);
        }
    }
    __syncthreads();
    scan_hist(cntA, cntB, tot, tid);   // also zeroes cntB

    // ---- scatter0: G -> LDS on bits 8-15 (matchany9, tail-guarded),
    //      fused count1 (bits 16-23) binned by destination wave ----
    for (int j = 0; j < 24; ++j) {
        int idx = base_idx + j * 64;
        bool valid = (idx < PP);
        unsigned u = 0u;
        if (valid) {
            u = rowU[idx];
            u = (u & 0x80000000u) ? ~u : (u | 0x80000000u);
        }
        unsigned d9 = ((u >> 8) & 255u) | (valid ? 0u : 256u);
        unsigned long long mm = matchany9(d9);
        if (valid) {
            int leader = __ffsll(mm) - 1;
            unsigned myrank = (unsigned)__popcll(mm & lt_mask);
            unsigned old = 0;
            if (lane == leader)
                old = atomicAdd(&cntA[wbase + (d9 & 255u)], (unsigned)__popcll(mm));
            old = (unsigned)__shfl((int)old, leader, 64);
            unsigned dest = old + myrank;
            keysL[dest] = u;
            atomicAdd(&cntB[(dest / WCHUNK) * 256 + ((u >> 16) & 255u)], 1u);
        }
    }
    __syncthreads();
    // pads: 216 keys 0xFFFFFFFF at keysL[PP..SNP) = pass-1 wave 15, digit 255
    if (tid == 0) cntB[15 * 256 + 255] += (SNP - PP);
    __syncthreads();
    scan_hist(cntB, cntA, tot, tid);   // zeroes cntA

    // ---- scatter1: LDS -> G(bA, padded) on bits 16-23 (matchany8, all valid),
    //      fused count2 (bits 24-31) binned by destination wave ----
    for (int j = 0; j < 24; ++j) {
        int idx = base_idx + j * 64;
        unsigned u = keysL[idx];
        unsigned d = (u >> 16) & 255u;
        unsigned long long mm = matchany8(d);
        int leader = __ffsll(mm) - 1;
        unsigned myrank = (unsigned)__popcll(mm & lt_mask);
        unsigned old = 0;
        if (lane == leader)
            old = atomicAdd(&cntB[wbase + d], (unsigned)__popcll(mm));
        old = (unsigned)__shfl((int)old, leader, 64);
        unsigned dest = old + myrank;
        bA[dest] = u;
        atomicAdd(&cntA[(dest / WCHUNK) * 256 + ((u >> 24) & 255u)], 1u);
    }
    __syncthreads();
    scan_hist(cntA, (unsigned*)0, tot, tid);

    // ---- scatter2: G -> fused dot on bits 24-31 (matchany8, all valid) ----
    float local = 0.f;
    for (int j = 0; j < 24; ++j) {
        int idx = base_idx + j * 64;
        unsigned u = bA[idx];
        unsigned d = (u >> 24) & 255u;
        unsigned long long mm = matchany8(d);
        int leader = __ffsll(mm) - 1;
        unsigned myrank = (unsigned)__popcll(mm & lt_mask);
        unsigned old = 0;
        if (lane == leader)
            old = atomicAdd(&cntA[wbase + d], (unsigned)__popcll(mm));
        old = (unsigned)__shfl((int)old, leader, 64);
        unsigned dest = old + myrank;
        if (dest < PP) {
            unsigned raw = (u & 0x80000000u) ? (u & 0x7FFFFFFFu) : ~u;
            local += wrow[dest] * __uint_as_float(raw);
        }
    }

    // block reduction of local
#pragma unroll
    for (int off = 32; off > 0; off >>= 1)
        local += __shfl_down(local, off, 64);
    if (lane == 0) red[wave] = local;
    __syncthreads();
    if (tid < WAVES) {
        float x = red[tid];
#pragma unroll
        for (int off = 8; off > 0; off >>= 1)
            x += __shfl_down(x, off, 64);
        if (tid == 0) out[k] = x;
    }
}

// ---------------------------------------------------------------------------
extern "C" void kernel_launch(void* const* d_in, const int* in_sizes, int n_in,
                              void* d_out, int out_size, void* d_ws, size_t ws_size,
                              hipStream_t stream) {
    const float* M      = (const float*)d_in[0];
    const float* Ws_in  = (const float*)d_in[1];
    const float* Wd_in  = (const float*)d_in[2];
    const float* Ws_out = (const float*)d_in[3];
    const float* Wd_out = (const float*)d_in[4];
    float* out = (float*)d_out;

    float* vec  = (float*)d_ws;                    // PP*VLD floats = 18.71 MB
    float* sm2T = vec + (size_t)PP * VLD;          // KK*PP floats  = 17.64 MB
    // k_sort scratch overlays vec (dead after k_gemm): KK*SNP u32 = 17.80 MB <= 18.71 MB
    unsigned* bufA = (unsigned*)d_ws;

    k_inner<<<1280, 256, 0, stream>>>(M, Ws_in, Wd_in, vec);

    dim3 g2((PP + GBP - 1) / GBP, (KK + GBK - 1) / GBK);
    k_gemm<<<g2, 256, 0, stream>>>(vec, Ws_out, sm2T);

    k_sort<<<KK, 1024, 0, stream>>>(sm2T, bufA, Wd_out, out);
}

// Round 14
// 251.224 us; speedup vs baseline: 1.5091x; 1.1143x over previous
//
#include <hip/hip_runtime.h>
#include <hip/hip_bf16.h>

#define DIMK 3
#define NPTS 30
#define KK   181
#define PP   24360
#define DEMB 190
#define VLD  192   // padded vec row stride (bf16 elements now)
#define SNP  24576 // padded sort-row length = 16*1536

typedef __attribute__((ext_vector_type(8))) short bf16x8;
typedef __attribute__((ext_vector_type(4))) float f32x4;

__device__ __forceinline__ ushort f2bf(float f) {
    unsigned u = __float_as_uint(f);
    u += 0x7FFFu + ((u >> 16) & 1u);
    return (ushort)(u >> 16);
}

// ---------------------------------------------------------------------------
// Kernel 0: convert Ws_out (181x190 fp32) -> Abf (192x192 bf16, zero-padded)
// ---------------------------------------------------------------------------
__global__ __launch_bounds__(256) void k_prep(
    const float* __restrict__ W, ushort* __restrict__ Abf)
{
    int i = blockIdx.x * 256 + threadIdx.x;   // grid 144*256 = 36864 exact
    int k = i / 192, d = i - k * 192;
    Abf[i] = (k < KK && d < DEMB) ? f2bf(W[k * DEMB + d]) : (ushort)0;
}

// ---------------------------------------------------------------------------
// Kernel 1: per-permutation inner embed -> vec (PP x VLD, bf16)
// [round-11 structure; output dtype now bf16]
// ---------------------------------------------------------------------------
__global__ __launch_bounds__(256, 5) void k_inner(
    const float* __restrict__ M,      // 3 x 30
    const float* __restrict__ Ws_in,  // 181 x 3
    const float* __restrict__ Wd_in,  // 181 x 27
    ushort* __restrict__ vec)         // PP x VLD (bf16)
{
    __shared__ float Gs[NPTS * 32];
    __shared__ float WsS[192 * 3];
    __shared__ float WdS[192 * 28];

    const int tid = threadIdx.x;

    for (int i = tid; i < 192 * 3; i += 256) WsS[i] = (i < KK * 3) ? Ws_in[i] : 0.f;
    for (int i = tid; i < 192 * 28; i += 256) {
        int k = i / 28, m = i - k * 28;
        WdS[i] = (k < KK && m < 27) ? Wd_in[k * 27 + m] : 0.f;
    }
    for (int e = tid; e < NPTS * 32; e += 256) {
        int a = e >> 5, b = e & 31;
        Gs[e] = (b < NPTS)
            ? (M[a] * M[b] + M[NPTS + a] * M[NPTS + b] + M[2 * NPTS + a] * M[2 * NPTS + b])
            : 0.f;
    }
    __syncthreads();

    const int wave = tid >> 6;
    const int lane = tid & 63;
    const int wid = blockIdx.x * 4 + wave;
    const int chunk = wid % 3;
    const int pstream = wid / 3;
    const int nstream = (chunk == 2) ? 1706 : 1707;
    const int k = chunk * 64 + lane;

    const float INF = __builtin_inff();
    const bool kvalid = (k < KK);
    const float w0 = WsS[k * 3 + 0];
    const float w1 = WsS[k * 3 + 1];
    const float w2 = WsS[k * 3 + 2];
    const float* wd = WdS + k * 28;

    for (int p = pstream; p < PP; p += nstream) {
        int i0 = p / 812;            // 812 = 29*28
        int r  = p - i0 * 812;
        int i1 = r / 28;
        int i2 = r - i1 * 28;
        int c0 = i0;
        int c1 = i1 + (i1 >= c0 ? 1 : 0);
        int lo = min(c0, c1), hi = max(c0, c1);
        int c2 = i2;
        if (c2 >= lo) c2++;
        if (c2 >= hi) c2++;

        ushort* vrow = vec + (long)p * VLD;

        if (chunk == 0 && lane < 9) {
            int i = lane / 3, j = lane % 3;
            int ci = (i == 0) ? c0 : ((i == 1) ? c1 : c2);
            int cj = (j == 0) ? c0 : ((j == 1) ? c1 : c2);
            vrow[lane] = f2bf(Gs[(ci << 5) + cj]);
        }

        const float* g0 = Gs + (c0 << 5);
        const float* g1 = Gs + (c1 << 5);
        const float* g2 = Gs + (c2 << 5);
        const unsigned xmask = (1u << c0) | (1u << c1) | (1u << c2);

        float v[32];
#pragma unroll
        for (int q = 0; q < 8; ++q) {
            float4 x0 = *(const float4*)&g0[q * 4];
            float4 x1 = *(const float4*)&g1[q * 4];
            float4 x2 = *(const float4*)&g2[q * 4];
            int j0 = q * 4;
            if (j0 + 0 < NPTS) { float val = w0 * x0.x + w1 * x1.x + w2 * x2.x;
                v[j0 + 0] = ((xmask >> (j0 + 0)) & 1u) ? INF : val; }
            if (j0 + 1 < NPTS) { float val = w0 * x0.y + w1 * x1.y + w2 * x2.y;
                v[j0 + 1] = ((xmask >> (j0 + 1)) & 1u) ? INF : val; }
            if (j0 + 2 < NPTS) { float val = w0 * x0.z + w1 * x1.z + w2 * x2.z;
                v[j0 + 2] = ((xmask >> (j0 + 2)) & 1u) ? INF : val; }
            if (j0 + 3 < NPTS) { float val = w0 * x0.w + w1 * x1.w + w2 * x2.w;
                v[j0 + 3] = ((xmask >> (j0 + 3)) & 1u) ? INF : val; }
        }
        v[30] = INF;
        v[31] = INF;

        // Batcher odd-even mergesort, n=32, ascending
#pragma unroll
        for (int pw = 1; pw < 32; pw <<= 1) {
#pragma unroll
            for (int kk = pw; kk >= 1; kk >>= 1) {
#pragma unroll
                for (int j = kk % pw; j + kk < 32; j += 2 * kk) {
#pragma unroll
                    for (int i = 0; i < kk; ++i) {
                        int a = i + j, b = i + j + kk;
                        if (a / (pw * 2) == b / (pw * 2)) {
                            float x = v[a], y = v[b];
                            v[a] = fminf(x, y);
                            v[b] = fmaxf(x, y);
                        }
                    }
                }
            }
        }

        if (kvalid) {
            v[27] = 0.f;
            float emb = 0.f;
#pragma unroll
            for (int q = 0; q < 7; ++q) {
                float4 w4 = *(const float4*)&wd[q * 4];
                emb += w4.x * v[q * 4] + w4.y * v[q * 4 + 1]
                     + w4.z * v[q * 4 + 2] + w4.w * v[q * 4 + 3];
            }
            vrow[9 + k] = f2bf(emb);
        } else if (k < 183) {
            vrow[9 + k] = 0;    // pad entries 190,191 stay zero
        }
    }
}

// ---------------------------------------------------------------------------
// Kernel 2: sm2T[k][p] = dot(vec[p], Ws_out[k]) via bf16 MFMA.
// Whole Ws_out (bf16, 192x192) resident in LDS (73.7 KB -> 2 blocks/CU);
// B-fragments (vec rows, d-contiguous) loaded straight from global into
// registers (vec read exactly once across the grid). Per wave: 16 p's,
// 12 k-subtiles x 6 K-chunks of mfma_f32_16x16x32_bf16.
// Fragment pattern = verified m97 gemm_bt: A[m=lane&15][d=quad*8+j],
// B[n=lane&15][d=quad*8+j], C col=lane&15, row=quad*4+reg.
// ---------------------------------------------------------------------------
__global__ __launch_bounds__(256) void k_gemm(
    const ushort* __restrict__ vecB,  // PP x 192 bf16
    const ushort* __restrict__ Abf,   // 192 x 192 bf16
    float* __restrict__ sm2T)         // 181 x PP fp32
{
    __shared__ ushort Asl[192 * 192];   // 73.7 KB

    const int tid = threadIdx.x;

    // stage A (contiguous float4 copy)
    {
        const float4* s4 = (const float4*)Abf;
        float4* d4 = (float4*)Asl;
        for (int i = tid; i < 192 * 192 * 2 / 16; i += 256) d4[i] = s4[i];
    }

    const int wave = tid >> 6;
    const int lane = tid & 63;
    const int n = lane & 15;        // p-local (B) / m (A) / C col
    const int quad = lane >> 4;
    const int pBase = blockIdx.x * 64 + wave * 16;
    const int p = pBase + n;

    // B fragments from global (all 6 K-chunks)
    bf16x8 bfrag[6];
    if (p < PP) {
        const ushort* row = vecB + (long)p * VLD;
#pragma unroll
        for (int kc = 0; kc < 6; ++kc)
            bfrag[kc] = *(const bf16x8*)&row[kc * 32 + quad * 8];
    } else {
        bf16x8 z = {0, 0, 0, 0, 0, 0, 0, 0};
#pragma unroll
        for (int kc = 0; kc < 6; ++kc) bfrag[kc] = z;
    }
    __syncthreads();

#pragma unroll
    for (int kt = 0; kt < 12; ++kt) {
        f32x4 acc = {0.f, 0.f, 0.f, 0.f};
        const ushort* arow = Asl + (kt * 16 + n) * 192;
#pragma unroll
        for (int kc = 0; kc < 6; ++kc) {
            bf16x8 afrag = *(const bf16x8*)&arow[kc * 32 + quad * 8];
            acc = __builtin_amdgcn_mfma_f32_16x16x32_bf16(afrag, bfrag[kc], acc, 0, 0, 0);
        }
        if (p < PP) {
            int k0 = kt * 16 + quad * 4;
#pragma unroll
            for (int r = 0; r < 4; ++r) {
                int kg = k0 + r;
                if (kg < KK) sm2T[(long)kg * PP + p] = acc[r];
            }
        }
    }
}

// ---------------------------------------------------------------------------
// Kernel 3: per-k LSD radix sort, high 24 bits, 3 passes [frozen, round 12]
// ---------------------------------------------------------------------------
#define WAVES  16
#define WCHUNK 1536

__device__ __forceinline__ unsigned long long matchany9(unsigned d) {
    unsigned long long m = ~0ull;
#pragma unroll
    for (int b = 0; b < 9; ++b) {
        unsigned bit = (d >> b) & 1u;
        unsigned long long bal = __ballot(bit);
        m &= bit ? bal : ~bal;
    }
    return m;
}

__device__ __forceinline__ unsigned long long matchany8(unsigned d) {
    unsigned long long m = ~0ull;
#pragma unroll
    for (int b = 0; b < 8; ++b) {
        unsigned bit = (d >> b) & 1u;
        unsigned long long bal = __ballot(bit);
        m &= bit ? bal : ~bal;
    }
    return m;
}

__device__ __forceinline__ void scan_hist(unsigned* cntC, unsigned* cntZ,
                                          unsigned* tot, int tid) {
    if (tid < 256) {
        unsigned run = 0;
        for (int w = 0; w < WAVES; ++w) {
            unsigned t = cntC[w * 256 + tid];
            cntC[w * 256 + tid] = run;
            run += t;
        }
        tot[tid] = run;
    }
    __syncthreads();
    if (tid < 64) {
        unsigned t0 = tot[tid * 4], t1 = tot[tid * 4 + 1];
        unsigned t2 = tot[tid * 4 + 2], t3 = tot[tid * 4 + 3];
        unsigned s = t0 + t1 + t2 + t3;
        unsigned sc = s;
#pragma unroll
        for (int off = 1; off < 64; off <<= 1) {
            unsigned o = (unsigned)__shfl_up((int)sc, off, 64);
            if (tid >= off) sc += o;
        }
        unsigned ex = sc - s;
        tot[tid * 4]     = ex + t0;
        tot[tid * 4 + 1] = ex + t0 + t1;
        tot[tid * 4 + 2] = ex + t0 + t1 + t2;
        tot[tid * 4 + 3] = ex + s;
    } else if (cntZ) {
        for (int i = tid - 64; i < WAVES * 256; i += 1024 - 64) cntZ[i] = 0;
    }
    __syncthreads();
    for (int i = tid; i < WAVES * 256; i += 1024) {
        int d = i & 255;
        unsigned db = (d == 0) ? 0u : tot[d - 1];
        cntC[i] += db;
    }
    __syncthreads();
}

__global__ __launch_bounds__(1024) void k_sort(
    float* sm2T,
    unsigned* bufA,           // 181 x SNP scratch
    const float* __restrict__ WdOut,
    float* __restrict__ out)
{
    __shared__ unsigned keysL[SNP];
    __shared__ unsigned cntA[WAVES * 256];
    __shared__ unsigned cntB[WAVES * 256];
    __shared__ unsigned tot[256];
    __shared__ float red[WAVES];

    const int tid  = threadIdx.x;
    const int wave = tid >> 6;
    const int lane = tid & 63;
    const int k    = blockIdx.x;

    const unsigned* rowU = (const unsigned*)sm2T + (long)k * PP;
    unsigned* bA         = bufA + (long)k * SNP;
    const float* wrow    = WdOut + (long)k * PP;

    const int base_idx = wave * WCHUNK + lane;
    const int wbase = wave * 256;
    const unsigned long long lt_mask = (1ull << lane) - 1ull;

    for (int i = tid; i < WAVES * 256; i += 1024) cntA[i] = 0;
    for (int i = PP + tid; i < SNP; i += 1024) keysL[i] = 0xFFFFFFFFu;
    __syncthreads();

    for (int j = 0; j < 24; ++j) {
        int idx = base_idx + j * 64;
        if (idx < PP) {
            unsigned u = rowU[idx];
            u = (u & 0x80000000u) ? ~u : (u | 0x80000000u);
            atomicAdd(&cntA[wbase + ((u >> 8) & 255u)], 1u);
        }
    }
    __syncthreads();
    scan_hist(cntA, cntB, tot, tid);

    for (int j = 0; j < 24; ++j) {
        int idx = base_idx + j * 64;
        bool valid = (idx < PP);
        unsigned u = 0u;
        if (valid) {
            u = rowU[idx];
            u = (u & 0x80000000u) ? ~u : (u | 0x80000000u);
        }
        unsigned d9 = ((u >> 8) & 255u) | (valid ? 0u : 256u);
        unsigned long long mm = matchany9(d9);
        if (valid) {
            int leader = __ffsll(mm) - 1;
            unsigned myrank = (unsigned)__popcll(mm & lt_mask);
            unsigned old = 0;
            if (lane == leader)
                old = atomicAdd(&cntA[wbase + (d9 & 255u)], (unsigned)__popcll(mm));
            old = (unsigned)__shfl((int)old, leader, 64);
            unsigned dest = old + myrank;
            keysL[dest] = u;
            atomicAdd(&cntB[(dest / WCHUNK) * 256 + ((u >> 16) & 255u)], 1u);
        }
    }
    __syncthreads();
    if (tid == 0) cntB[15 * 256 + 255] += (SNP - PP);
    __syncthreads();
    scan_hist(cntB, cntA, tot, tid);

    for (int j = 0; j < 24; ++j) {
        int idx = base_idx + j * 64;
        unsigned u = keysL[idx];
        unsigned d = (u >> 16) & 255u;
        unsigned long long mm = matchany8(d);
        int leader = __ffsll(mm) - 1;
        unsigned myrank = (unsigned)__popcll(mm & lt_mask);
        unsigned old = 0;
        if (lane == leader)
            old = atomicAdd(&cntB[wbase + d], (unsigned)__popcll(mm));
        old = (unsigned)__shfl((int)old, leader, 64);
        unsigned dest = old + myrank;
        bA[dest] = u;
        atomicAdd(&cntA[(dest / WCHUNK) * 256 + ((u >> 24) & 255u)], 1u);
    }
    __syncthreads();
    scan_hist(cntA, (unsigned*)0, tot, tid);

    float local = 0.f;
    for (int j = 0; j < 24; ++j) {
        int idx = base_idx + j * 64;
        unsigned u = bA[idx];
        unsigned d = (u >> 24) & 255u;
        unsigned long long mm = matchany8(d);
        int leader = __ffsll(mm) - 1;
        unsigned myrank = (unsigned)__popcll(mm & lt_mask);
        unsigned old = 0;
        if (lane == leader)
            old = atomicAdd(&cntA[wbase + d], (unsigned)__popcll(mm));
        old = (unsigned)__shfl((int)old, leader, 64);
        unsigned dest = old + myrank;
        if (dest < PP) {
            unsigned raw = (u & 0x80000000u) ? (u & 0x7FFFFFFFu) : ~u;
            local += wrow[dest] * __uint_as_float(raw);
        }
    }

#pragma unroll
    for (int off = 32; off > 0; off >>= 1)
        local += __shfl_down(local, off, 64);
    if (lane == 0) red[wave] = local;
    __syncthreads();
    if (tid < WAVES) {
        float x = red[tid];
#pragma unroll
        for (int off = 8; off > 0; off >>= 1)
            x += __shfl_down(x, off, 64);
        if (tid == 0) out[k] = x;
    }
}

// ---------------------------------------------------------------------------
extern "C" void kernel_launch(void* const* d_in, const int* in_sizes, int n_in,
                              void* d_out, int out_size, void* d_ws, size_t ws_size,
                              hipStream_t stream) {
    const float* M      = (const float*)d_in[0];
    const float* Ws_in  = (const float*)d_in[1];
    const float* Wd_in  = (const float*)d_in[2];
    const float* Ws_out = (const float*)d_in[3];
    const float* Wd_out = (const float*)d_in[4];
    float* out = (float*)d_out;

    // workspace layout (35.5 MB total, < previous 36.3 MB):
    // [0, 17.79 MB):  bufA (k_sort scratch, 181 x SNP u32)
    //                 vecB (PP x 192 bf16 = 9.35 MB) overlays its head;
    //                 vec is dead before k_sort runs.
    // [17.79, 35.43): sm2T (181 x PP fp32)
    // [35.43, +74KB): Abf (192 x 192 bf16)
    char* ws = (char*)d_ws;
    ushort*   vecB = (ushort*)ws;
    unsigned* bufA = (unsigned*)ws;
    float*    sm2T = (float*)(ws + (size_t)KK * SNP * 4);
    ushort*   Abf  = (ushort*)(ws + (size_t)KK * SNP * 4 + (size_t)KK * PP * 4);

    k_prep<<<144, 256, 0, stream>>>(Ws_out, Abf);

    k_inner<<<1280, 256, 0, stream>>>(M, Ws_in, Wd_in, vecB);

    k_gemm<<<(PP + 63) / 64, 256, 0, stream>>>(vecB, Abf, sm2T);

    k_sort<<<KK, 1024, 0, stream>>>(sm2T, bufA, Wd_out, out);
}